// Round 6
// baseline (226.055 us; speedup 1.0000x reference)
//
#include <hip/hip_runtime.h>
#include <hip/hip_bf16.h>
#include <float.h>

// Problem constants
#define N_ROWS 32768          // 32 * 1024 query vectors
#define DIMS   64
#define K_EMB  8192
#define NT32   (K_EMB / 32)   // 256 column tiles of 32
#define NTH32  (NT32 / 2)     // 128 tiles per K-half
#define TSTAGE 4              // tiles per stage (4 * 8KB = 32KB)
#define NSTAGE (NTH32 / TSTAGE) // 32
// bound: split-bf16 err 6.5e-4 + 7-bit mantissa steal 1e-3, x2 values
#define GAP_THR 4.0e-3f

typedef __attribute__((ext_vector_type(8)))  short s8v;   // 8 bf16 (A/B frag)
typedef __attribute__((ext_vector_type(16))) float f16v;  // 32x32 C/D frag
typedef __attribute__((ext_vector_type(4)))  int   i4v;   // 16B load unit

// Workspace layout (bytes)
#define WS_EFRAG 0                              // 256 tiles * 8KB = 2 MiB
#define WS_EN2   (2 * 1024 * 1024)              // 8192 f32: -0.5*||e||^2
#define WS_IDX   (WS_EN2 + K_EMB * 4)           // 32768 i32 (merged idx)
#define WS_KEY   (WS_IDX + N_ROWS * 4)          // 32768 u64 fixup keys
#define WS_BH    (WS_KEY + N_ROWS * 8)          // [2][N] best per K-half (packed f32)
#define WS_SH    (WS_BH + 2 * N_ROWS * 4)       // [2][N] second
#define WS_CH    (WS_SH + 2 * N_ROWS * 4)       // [2][N] idx
#define WS_CTL   (WS_CH + 2 * N_ROWS * 4)       // {double loss; int wl_count; int done}
#define WS_WL    (WS_CTL + 16)                  // worklist

// Output layout (float32 elements): [quantized | loss | indices]
#define OUT_LOSS (N_ROWS * DIMS)
#define OUT_IDX  (N_ROWS * DIMS + 1)

__device__ inline short bfh(float v) {
    __hip_bfloat16 h = __float2bfloat16(v);
    return __builtin_bit_cast(short, h);
}
__device__ inline float bff(short s) {
    __hip_bfloat16 h = __builtin_bit_cast(__hip_bfloat16, s);
    return __bfloat162float(h);
}

// ---------------------------------------------------------------------------
// Prep: embeddings -> 32x32x16 MFMA B-frag layout (hi/lo split) + -||e||^2/2.
// B-frag: lane holds B[k=(lane>>5)*8+j][n=lane&31]; k-chunk kc covers dims
// kc*16..+15. Frags 0..3 = hi kc, 4..7 = lo kc. [tile][frag][lane][16B].
// ---------------------------------------------------------------------------
__global__ void vq_prep(const float* __restrict__ emb, short* __restrict__ efrag,
                        float* __restrict__ en2) {
    int gid = blockIdx.x * 256 + threadIdx.x;   // NT32*64 = 16384 threads
    int t = gid >> 6, lane = gid & 63;
    int n = lane & 31, q2 = lane >> 5;
    const float* er = emb + (size_t)(t * 32 + n) * DIMS + q2 * 8;
    s8v hi[4], lo[4];
    float ss = 0.f;
#pragma unroll
    for (int kc = 0; kc < 4; ++kc) {
#pragma unroll
        for (int j = 0; j < 8; ++j) {
            float v = er[kc * 16 + j];
            ss += v * v;
            short h = bfh(v); lo[kc][j] = bfh(v - bff(h)); hi[kc][j] = h;
        }
    }
    s8v* base = (s8v*)efrag + (size_t)t * 8 * 64;
#pragma unroll
    for (int kc = 0; kc < 4; ++kc) {
        base[kc * 64 + lane]       = hi[kc];
        base[(4 + kc) * 64 + lane] = lo[kc];
    }
    ss += __shfl_xor(ss, 32, 64);   // combine the two k-half lanes of this row
    if (q2 == 0) en2[t * 32 + n] = -0.5f * ss;
}

// ---------------------------------------------------------------------------
// Phase 1: LDS-staged split-bf16 32x32x16 MFMA + 3-op argmax epilogue.
// Grid (256, 2): x = row-block (4 waves x 32 rows = 128), y = K-half.
// Tile index embedded in low 7 mantissa bits (and_or / max / med3 per elem).
// ---------------------------------------------------------------------------
__global__ __launch_bounds__(256, 2) void vq_phase1(
    const float* __restrict__ x, const short* __restrict__ efrag,
    const float* __restrict__ en2,
    float* __restrict__ bh, float* __restrict__ sh, int* __restrict__ ch) {
    __shared__ __align__(16) char lds[2][TSTAGE * 8192];   // 64 KB
    int tid = threadIdx.x, wid = tid >> 6, lane = tid & 63;
    int n = lane & 31, q2 = lane >> 5;
    int kh = blockIdx.y;
    int row0 = blockIdx.x * 128 + wid * 32;

    // A-frags: A[m=lane&31][k=(lane>>5)*8+j], hi/lo, 4 k-chunks of 16 dims.
    s8v ahi[4], alo[4];
    {
        const float* xr = x + (size_t)(row0 + n) * DIMS + q2 * 8;
#pragma unroll
        for (int kc = 0; kc < 4; ++kc)
#pragma unroll
            for (int j = 0; j < 8; ++j) {
                float v = xr[kc * 16 + j];
                short h = bfh(v); alo[kc][j] = bfh(v - bff(h)); ahi[kc][j] = h;
            }
    }

    float best[16], sec[16];
#pragma unroll
    for (int r = 0; r < 16; ++r) { best[r] = -FLT_MAX; sec[r] = -FLT_MAX; }

    const char* gsrc = (const char*)efrag + (size_t)kh * NTH32 * 8192;
    const float* ep = en2 + kh * (K_EMB / 2) + n;

    // preload stage 0 (32 KB)
#pragma unroll
    for (int i = 0; i < 8; ++i)
        __builtin_amdgcn_global_load_lds(
            (const __attribute__((address_space(1))) void*)(gsrc + i * 4096 + tid * 16),
            (__attribute__((address_space(3))) void*)(&lds[0][i * 4096 + tid * 16]),
            16, 0, 0);
    __syncthreads();

    for (int s = 0; s < NSTAGE; ++s) {
        int pb = s & 1;
        if (s + 1 < NSTAGE) {
            const char* gn = gsrc + (size_t)(s + 1) * TSTAGE * 8192;
#pragma unroll
            for (int i = 0; i < 8; ++i)
                __builtin_amdgcn_global_load_lds(
                    (const __attribute__((address_space(1))) void*)(gn + i * 4096 + tid * 16),
                    (__attribute__((address_space(3))) void*)(&lds[pb ^ 1][i * 4096 + tid * 16]),
                    16, 0, 0);
        }
        const i4v* B = (const i4v*)(lds[pb]);
        int tg0 = s * TSTAGE;   // tile within this K-half
#pragma unroll
        for (int tp = 0; tp < TSTAGE; tp += 2) {   // two tiles interleaved
            i4v bb0[8], bb1[8];
#pragma unroll
            for (int f = 0; f < 8; ++f) {
                bb0[f] = B[(tp + 0) * 512 + f * 64 + lane];
                bb1[f] = B[(tp + 1) * 512 + f * 64 + lane];
            }
            float c00 = ep[(tg0 + tp + 0) * 32];
            float c01 = ep[(tg0 + tp + 1) * 32];
            f16v acc0, acc1;
#pragma unroll
            for (int r = 0; r < 16; ++r) { acc0[r] = c00; acc1[r] = c01; }
#define STEP(Aop, F) \
            acc0 = __builtin_amdgcn_mfma_f32_32x32x16_bf16(Aop, __builtin_bit_cast(s8v, bb0[F]), acc0, 0, 0, 0); \
            acc1 = __builtin_amdgcn_mfma_f32_32x32x16_bf16(Aop, __builtin_bit_cast(s8v, bb1[F]), acc1, 0, 0, 0);
            STEP(ahi[0], 0) STEP(ahi[1], 1) STEP(ahi[2], 2) STEP(ahi[3], 3)   // hi.hi
            STEP(ahi[0], 4) STEP(ahi[1], 5) STEP(ahi[2], 6) STEP(ahi[3], 7)   // hi_x.lo_e
            STEP(alo[0], 0) STEP(alo[1], 1) STEP(alo[2], 2) STEP(alo[3], 3)   // lo_x.hi_e
#undef STEP
            int tb0 = (~(tg0 + tp + 0)) & 0x7F;
            int tb1 = (~(tg0 + tp + 1)) & 0x7F;
#pragma unroll
            for (int r = 0; r < 16; ++r) {
                float v0 = __int_as_float((__float_as_int(acc0[r]) & 0xFFFFFF80) | tb0);
                sec[r]  = __builtin_amdgcn_fmed3f(v0, best[r], sec[r]);
                best[r] = fmaxf(best[r], v0);
                float v1 = __int_as_float((__float_as_int(acc1[r]) & 0xFFFFFF80) | tb1);
                sec[r]  = __builtin_amdgcn_fmed3f(v1, best[r], sec[r]);
                best[r] = fmaxf(best[r], v1);
            }
        }
        __syncthreads();
    }

    // Reduce (best, col, sec) across the 32 col-lanes; rows per C/D map:
    // row = (r&3) + 8*(r>>2) + 4*q2, col = lane&31.
#pragma unroll
    for (int r = 0; r < 16; ++r) {
        float b = best[r], s2 = sec[r];
        int c = ((~__float_as_int(b)) & 0x7F) * 32 + n;   // col within K-half
#pragma unroll
        for (int off = 1; off < 32; off <<= 1) {
            float ob = __shfl_xor(b, off, 64);
            float os = __shfl_xor(s2, off, 64);
            int   oc = __shfl_xor(c, off, 64);
            float nb = fmaxf(b, ob);
            float ns = fmaxf(fminf(b, ob), fmaxf(s2, os));
            bool take = (ob > b) || (ob == b && oc < c);
            c = take ? oc : c;
            b = nb; s2 = ns;
        }
        if (n == 0) {
            int row = row0 + (r & 3) + 8 * (r >> 2) + 4 * q2;
            int o = kh * N_ROWS + row;
            bh[o] = b; sh[o] = s2; ch[o] = kh * (K_EMB / 2) + c;
        }
    }
}

// ---------------------------------------------------------------------------
// Merge the two K-halves per row; zero fixup keys; build worklist.
// ---------------------------------------------------------------------------
__global__ void vq_merge(const float* __restrict__ bh, const float* __restrict__ sh,
                         const int* __restrict__ ch, int* __restrict__ idx_buf,
                         unsigned long long* __restrict__ key8,
                         int* __restrict__ wl, int* __restrict__ wl_count) {
    int row = blockIdx.x * 256 + threadIdx.x;
    float b0 = bh[row], b1 = bh[N_ROWS + row];
    float s0 = sh[row], s1 = sh[N_ROWS + row];
    int   c0 = ch[row], c1 = ch[N_ROWS + row];
    float nb = fmaxf(b0, b1);
    float ns = fmaxf(fminf(b0, b1), fmaxf(s0, s1));
    int c = (b1 > b0) ? c1 : c0;
    idx_buf[row] = c;
    key8[row] = 0ULL;
    if (nb - ns < GAP_THR) {
        int pos = atomicAdd(wl_count, 1);
        wl[pos] = row;
    }
}

// ---------------------------------------------------------------------------
// Fixup: exact fp32 rescan, 8 col-chunk blocks per flagged row, merged via
// atomicMax on packed (sortable(f) << 32 | ~idx) — exact, ties -> low idx.
// ---------------------------------------------------------------------------
__global__ __launch_bounds__(256) void vq_fixup(
    const float* __restrict__ x, const float* __restrict__ emb,
    const float* __restrict__ en2, unsigned long long* __restrict__ key8,
    const int* __restrict__ wl, const int* __restrict__ wl_count) {
    __shared__ float4 sx[16];
    __shared__ float sbf[4];
    __shared__ int   sbc[4];
    int tid = threadIdx.x, wid = tid >> 6, lane = tid & 63;
    int cnt = *wl_count;
    for (int wi = blockIdx.x; wi < cnt * 8; wi += gridDim.x) {
        int row = wl[wi >> 3];
        int cbase = (wi & 7) * (K_EMB / 8);
        if (tid < 16) sx[tid] = ((const float4*)(x + (size_t)row * DIMS))[tid];
        __syncthreads();
        float bf_ = -FLT_MAX;
        int bc_ = 0;
        for (int c = cbase + tid; c < cbase + K_EMB / 8; c += 256) {
            const float4* er = (const float4*)(emb + (size_t)c * DIMS);
            float d = 0.f;
#pragma unroll
            for (int qq = 0; qq < 16; ++qq) {
                float4 e = er[qq];
                float4 xx = sx[qq];
                d += e.x * xx.x + e.y * xx.y + e.z * xx.z + e.w * xx.w;
            }
            float f = d + en2[c];
            if (f > bf_) { bf_ = f; bc_ = c; }
        }
#pragma unroll
        for (int off = 1; off < 64; off <<= 1) {
            float of = __shfl_xor(bf_, off, 64);
            int   oc = __shfl_xor(bc_, off, 64);
            if (of > bf_ || (of == bf_ && oc < bc_)) { bf_ = of; bc_ = oc; }
        }
        if (lane == 0) { sbf[wid] = bf_; sbc[wid] = bc_; }
        __syncthreads();
        if (tid == 0) {
            float b = sbf[0]; int c = sbc[0];
#pragma unroll
            for (int i = 1; i < 4; ++i)
                if (sbf[i] > b || (sbf[i] == b && sbc[i] < c)) { b = sbf[i]; c = sbc[i]; }
            unsigned int u = __float_as_uint(b);
            unsigned int sb = ((int)u < 0) ? ~u : (u | 0x80000000u);
            unsigned long long key = ((unsigned long long)sb << 32) | (unsigned int)(~c);
            atomicMax(&key8[row], key);
        }
        __syncthreads();
    }
}

// ---------------------------------------------------------------------------
// Gather quantized rows, squared error, indices; last block finalizes loss.
// ---------------------------------------------------------------------------
__global__ void vq_gather(const float* __restrict__ x, const float* __restrict__ emb,
                          const int* __restrict__ idx_buf,
                          const unsigned long long* __restrict__ key8,
                          float* __restrict__ out, double* __restrict__ loss_acc,
                          int* __restrict__ done_ctr) {
    int row = blockIdx.x * blockDim.x + threadIdx.x;
    unsigned long long k = key8[row];
    int idx = k ? (int)(~(unsigned int)k) : idx_buf[row];
    const float4* ev = (const float4*)(emb + (size_t)idx * DIMS);
    const float4* xv = (const float4*)(x + (size_t)row * DIMS);
    float4* ov = (float4*)(out + (size_t)row * DIMS);
    float s = 0.f;
#pragma unroll
    for (int qq = 0; qq < 16; ++qq) {
        float4 ee = ev[qq];
        float4 xx = xv[qq];
        float dx = ee.x - xx.x, dy = ee.y - xx.y, dz = ee.z - xx.z, dw = ee.w - xx.w;
        s += dx * dx + dy * dy + dz * dz + dw * dw;
        ov[qq] = ee;
    }
#pragma unroll
    for (int off = 32; off > 0; off >>= 1) s += __shfl_down(s, off, 64);
    if ((threadIdx.x & 63) == 0) atomicAdd(loss_acc, (double)s);
    out[OUT_IDX + row] = (float)idx;
    __syncthreads();
    if (threadIdx.x == 0) {
        __threadfence();
        int d = atomicAdd(done_ctr, 1);
        if (d == (int)gridDim.x - 1) {
            double tot = atomicAdd(loss_acc, 0.0);
            out[OUT_LOSS] = (float)(1.25 * tot / (double)(N_ROWS * DIMS));
        }
    }
}

// ---------------------------------------------------------------------------
extern "C" void kernel_launch(void* const* d_in, const int* in_sizes, int n_in,
                              void* d_out, int out_size, void* d_ws, size_t ws_size,
                              hipStream_t stream) {
    const float* x   = (const float*)d_in[0];
    const float* emb = (const float*)d_in[1];
    float* out = (float*)d_out;
    char*  ws  = (char*)d_ws;

    short* efrag   = (short*)(ws + WS_EFRAG);
    float* en2     = (float*)(ws + WS_EN2);
    int*   idx_buf = (int*)(ws + WS_IDX);
    unsigned long long* key8 = (unsigned long long*)(ws + WS_KEY);
    float* bhb     = (float*)(ws + WS_BH);
    float* shb     = (float*)(ws + WS_SH);
    int*   chb     = (int*)(ws + WS_CH);
    double* loss_acc = (double*)(ws + WS_CTL);
    int*   wl_count  = (int*)(ws + WS_CTL + 8);
    int*   done_ctr  = (int*)(ws + WS_CTL + 12);
    int*   wl        = (int*)(ws + WS_WL);

    hipMemsetAsync(ws + WS_CTL, 0, 16, stream);   // loss + wl_count + done

    vq_prep<<<(NT32 * 64) / 256, 256, 0, stream>>>(emb, efrag, en2);     // 64 blocks
    vq_phase1<<<dim3(N_ROWS / 128, 2), 256, 0, stream>>>(x, efrag, en2, bhb, shb, chb);
    vq_merge<<<N_ROWS / 256, 256, 0, stream>>>(bhb, shb, chb, idx_buf, key8, wl, wl_count);
    vq_fixup<<<2048, 256, 0, stream>>>(x, emb, en2, key8, wl, wl_count);
    vq_gather<<<N_ROWS / 256, 256, 0, stream>>>(x, emb, idx_buf, key8, out, loss_acc, done_ctr);
}